// Round 1
// baseline (883.618 us; speedup 1.0000x reference)
//
#include <hip/hip_runtime.h>

#define HD 128      // hidden / feature dim
#define CLS 10      // num classes

// ---------------- CSR build ----------------
__global__ __launch_bounds__(256) void k_deg(const int* __restrict__ dst, int* __restrict__ deg, int E) {
    int e = blockIdx.x * 256 + threadIdx.x;
    if (e < E) atomicAdd(&deg[dst[e]], 1);
}

__global__ __launch_bounds__(256) void k_alloc(const int* __restrict__ deg, int* __restrict__ start,
                                               int* __restrict__ cur, int* __restrict__ cursor, int N) {
    int n = blockIdx.x * 256 + threadIdx.x;
    int lane = threadIdx.x & 63;
    int d = (n < N) ? deg[n] : 0;
    int x = d;
    #pragma unroll
    for (int off = 1; off < 64; off <<= 1) {
        int y = __shfl_up(x, off);
        if (lane >= off) x += y;
    }
    int total = __shfl(x, 63);          // wave total
    int base = 0;
    if (lane == 63) base = atomicAdd(cursor, total);
    base = __shfl(base, 63);
    if (n < N) {
        int s = base + x - d;           // exclusive prefix within wave
        start[n] = s;
        cur[n] = s;
    }
}

__global__ __launch_bounds__(256) void k_fill(const int* __restrict__ src, const int* __restrict__ dst,
                                              int* __restrict__ cur, int* __restrict__ eidx, int E) {
    int e = blockIdx.x * 256 + threadIdx.x;
    if (e < E) {
        int p = atomicAdd(&cur[dst[e]], 1);
        eidx[p] = src[e];
    }
}

// ---------------- aggregation: agg[n,:] = sum over in-edges of h[src,:] ----------------
// one 64-lane wave per node; lane covers 2 floats (float2) of the 128-wide row
__global__ __launch_bounds__(256) void k_agg(const float* __restrict__ h, const int* __restrict__ start,
                                             const int* __restrict__ deg, const int* __restrict__ eidx,
                                             float* __restrict__ agg, int N) {
    int w = blockIdx.x * 4 + (threadIdx.x >> 6);
    if (w >= N) return;
    int lane = threadIdx.x & 63;
    int s = start[w];
    int d = deg[w];
    const float2* h2 = (const float2*)h;
    float2 acc = make_float2(0.f, 0.f);
    for (int e = 0; e < d; ++e) {
        int sn = eidx[s + e];
        float2 v = h2[(size_t)sn * 64 + lane];
        acc.x += v.x;
        acc.y += v.y;
    }
    ((float2*)agg)[(size_t)w * 64 + lane] = acc;
}

// ---------------- fused conv: hout = relu(agg @ Wr^T + br + hin @ Wroot^T) ----------------
// block: 256 threads -> 32 rows x 128 cols tile; thread: 4 rows x 4 cols.
// NOTE: hout may alias agg (all reads of a block's rows complete before its stores).
__device__ inline void fma4(float4& a, float s, const float4& v) {
    a.x += s * v.x; a.y += s * v.y; a.z += s * v.z; a.w += s * v.w;
}

__global__ __launch_bounds__(256) void k_conv(const float* agg, const float* __restrict__ hin,
                                              const float* __restrict__ Wr, const float* __restrict__ br,
                                              const float* __restrict__ Wroot, float* hout, int N) {
    __shared__ float sA[2][32][32];     // [agg|h][row][k]  8 KB
    __shared__ float sB[2][32][128];    // [Wr|Wroot][k][j] 32 KB (transposed for j-contig reads)
    int tid = threadIdx.x;
    int n0 = blockIdx.x * 32;
    int jg = tid & 31;                  // j0 = jg*4
    int rg = tid >> 5;                  // r0 = rg*4

    float4 acc[4];
    #pragma unroll
    for (int r = 0; r < 4; ++r) acc[r] = make_float4(0.f, 0.f, 0.f, 0.f);

    for (int kc = 0; kc < HD; kc += 32) {
        // ---- stage A tiles (32 rows x 32 k, both matrices) ----
        {
            int ar = tid >> 3;           // 0..31
            int ak = (tid & 7) * 4;      // 0..28
            int an = n0 + ar;
            float4 va = make_float4(0.f, 0.f, 0.f, 0.f), vh = va;
            if (an < N) {
                va = *(const float4*)&agg[(size_t)an * HD + kc + ak];
                vh = *(const float4*)&hin[(size_t)an * HD + kc + ak];
            }
            *(float4*)&sA[0][ar][ak] = va;
            *(float4*)&sA[1][ar][ak] = vh;
        }
        // ---- stage B tiles transposed: sB[m][k][j] ----
        {
            int bj = tid & 127;
            int kh = (tid >> 7) * 16;
            #pragma unroll
            for (int m = 0; m < 2; ++m) {
                const float* W = m ? Wroot : Wr;
                #pragma unroll
                for (int q = 0; q < 4; ++q) {
                    float4 w = *(const float4*)&W[bj * HD + kc + kh + q * 4];
                    sB[m][kh + q * 4 + 0][bj] = w.x;
                    sB[m][kh + q * 4 + 1][bj] = w.y;
                    sB[m][kh + q * 4 + 2][bj] = w.z;
                    sB[m][kh + q * 4 + 3][bj] = w.w;
                }
            }
        }
        __syncthreads();
        // ---- compute ----
        #pragma unroll
        for (int kk = 0; kk < 32; kk += 4) {
            float4 wr[4], wo[4];
            #pragma unroll
            for (int q = 0; q < 4; ++q) {
                wr[q] = *(float4*)&sB[0][kk + q][jg * 4];
                wo[q] = *(float4*)&sB[1][kk + q][jg * 4];
            }
            #pragma unroll
            for (int r = 0; r < 4; ++r) {
                float4 a = *(float4*)&sA[0][rg * 4 + r][kk];
                float4 b = *(float4*)&sA[1][rg * 4 + r][kk];
                fma4(acc[r], a.x, wr[0]); fma4(acc[r], a.y, wr[1]);
                fma4(acc[r], a.z, wr[2]); fma4(acc[r], a.w, wr[3]);
                fma4(acc[r], b.x, wo[0]); fma4(acc[r], b.y, wo[1]);
                fma4(acc[r], b.z, wo[2]); fma4(acc[r], b.w, wo[3]);
            }
        }
        __syncthreads();
    }
    // ---- epilogue: bias + relu + store ----
    float4 bias = *(const float4*)&br[jg * 4];
    #pragma unroll
    for (int r = 0; r < 4; ++r) {
        int n = n0 + rg * 4 + r;
        if (n < N) {
            float4 v;
            v.x = fmaxf(acc[r].x + bias.x, 0.f);
            v.y = fmaxf(acc[r].y + bias.y, 0.f);
            v.z = fmaxf(acc[r].z + bias.z, 0.f);
            v.w = fmaxf(acc[r].w + bias.w, 0.f);
            *(float4*)&hout[(size_t)n * HD + jg * 4] = v;
        }
    }
}

// ---------------- pooling: emb[g,:] += run sums (batch is sorted) ----------------
#define PCH 512
__global__ __launch_bounds__(128) void k_pool(const float* __restrict__ h, const int* __restrict__ batch,
                                              float* __restrict__ emb, int* __restrict__ cnt, int N) {
    __shared__ int sb[PCH];
    int t = threadIdx.x;    // feature index 0..127
    int n0 = blockIdx.x * PCH;
    int nloc = min(PCH, N - n0);
    for (int i = t; i < nloc; i += 128) sb[i] = batch[n0 + i];
    __syncthreads();
    float run = 0.f;
    int runlen = 0;
    int gprev = sb[0];
    const float* hp = h + (size_t)n0 * HD + t;
    for (int i = 0; i < nloc; ++i) {
        int g = sb[i];
        if (g != gprev) {
            atomicAdd(&emb[gprev * HD + t], run);
            if (t == 0) atomicAdd(&cnt[gprev], runlen);
            run = 0.f; runlen = 0; gprev = g;
        }
        run += hp[(size_t)i * HD];
        runlen++;
    }
    atomicAdd(&emb[gprev * HD + t], run);
    if (t == 0) atomicAdd(&cnt[gprev], runlen);
}

// ---------------- final: out[g,c] = dot(emb[g]/max(cnt,1), lin_w[c]) + lin_b[c] ----------------
__global__ __launch_bounds__(128) void k_final(const float* __restrict__ emb, const int* __restrict__ cnt,
                                               const float* __restrict__ lw, const float* __restrict__ lb,
                                               float* __restrict__ out, int G) {
    int idx = blockIdx.x * 128 + threadIdx.x;
    if (idx >= G * CLS) return;
    int g = idx / CLS, c = idx % CLS;
    const float* e = emb + g * HD;
    const float* w = lw + c * HD;
    float s = 0.f;
    #pragma unroll
    for (int k = 0; k < HD; ++k) s += e[k] * w[k];
    float cc = fmaxf((float)cnt[g], 1.0f);
    out[idx] = s / cc + lb[c];
}

extern "C" void kernel_launch(void* const* d_in, const int* in_sizes, int n_in,
                              void* d_out, int out_size, void* d_ws, size_t ws_size,
                              hipStream_t stream) {
    const float* x     = (const float*)d_in[0];
    const int*   ei    = (const int*)d_in[1];
    const int*   batch = (const int*)d_in[2];
    const float* Wr[4]  = {(const float*)d_in[3], (const float*)d_in[6], (const float*)d_in[9],  (const float*)d_in[12]};
    const float* brl[4] = {(const float*)d_in[4], (const float*)d_in[7], (const float*)d_in[10], (const float*)d_in[13]};
    const float* Wo[4]  = {(const float*)d_in[5], (const float*)d_in[8], (const float*)d_in[11], (const float*)d_in[14]};
    const float* lw = (const float*)d_in[15];
    const float* lb = (const float*)d_in[16];
    float* out = (float*)d_out;

    int N = in_sizes[0] / HD;
    int E = in_sizes[1] / 2;
    int G = out_size / CLS;
    const int* src = ei;
    const int* dst = ei + E;

    // ---- workspace layout (zero-needed regions first, contiguous) ----
    char* ws = (char*)d_ws;
    size_t off = 0;
    auto alloc = [&](size_t bytes) -> char* {
        char* p = ws + off;
        off += (bytes + 255) & ~(size_t)255;
        return p;
    };
    int*   deg    = (int*)alloc((size_t)N * 4);        // zeroed
    int*   cursor = (int*)alloc(16);                   // zeroed
    float* emb    = (float*)alloc((size_t)G * HD * 4); // zeroed
    int*   cnt    = (int*)alloc((size_t)G * 4);        // zeroed
    size_t zero_bytes = off;
    int*   startp = (int*)alloc((size_t)N * 4);
    int*   curp   = (int*)alloc((size_t)N * 4);
    int*   eidx   = (int*)alloc((size_t)E * 4);
    float* bufA   = (float*)alloc((size_t)N * HD * 4);
    float* bufB   = (float*)alloc((size_t)N * HD * 4);

    hipMemsetAsync(d_ws, 0, zero_bytes, stream);

    // ---- CSR build ----
    k_deg<<<(E + 255) / 256, 256, 0, stream>>>(dst, deg, E);
    k_alloc<<<(N + 255) / 256, 256, 0, stream>>>(deg, startp, curp, cursor, N);
    k_fill<<<(E + 255) / 256, 256, 0, stream>>>(src, dst, curp, eidx, E);

    // ---- 4 GraphConv layers ----
    const float* hin = x;
    for (int l = 0; l < 4; ++l) {
        float* dbuf = (l & 1) ? bufB : bufA;
        k_agg<<<(N + 3) / 4, 256, 0, stream>>>(hin, startp, deg, eidx, dbuf, N);
        k_conv<<<(N + 31) / 32, 256, 0, stream>>>(dbuf, hin, Wr[l], brl[l], Wo[l], dbuf, N);
        hin = dbuf;
    }

    // ---- pooling + final linear ----
    k_pool<<<(N + PCH - 1) / PCH, 128, 0, stream>>>(hin, batch, emb, cnt, N);
    k_final<<<(G * CLS + 127) / 128, 128, 0, stream>>>(emb, cnt, lw, lb, out, G);
}

// Round 2
// 696.812 us; speedup vs baseline: 1.2681x; 1.2681x over previous
//
#include <hip/hip_runtime.h>

#define HD 128      // hidden / feature dim
#define CLS 10      // num classes

// ---------------- CSR build ----------------
__global__ __launch_bounds__(256) void k_deg(const int* __restrict__ dst, int* __restrict__ deg, int E) {
    int e = blockIdx.x * 256 + threadIdx.x;
    if (e < E) atomicAdd(&deg[dst[e]], 1);
}

__global__ __launch_bounds__(256) void k_alloc(const int* __restrict__ deg, int* __restrict__ start,
                                               int* __restrict__ cur, int* __restrict__ cursor, int N) {
    int n = blockIdx.x * 256 + threadIdx.x;
    int lane = threadIdx.x & 63;
    int d = (n < N) ? deg[n] : 0;
    int x = d;
    #pragma unroll
    for (int off = 1; off < 64; off <<= 1) {
        int y = __shfl_up(x, off);
        if (lane >= off) x += y;
    }
    int total = __shfl(x, 63);          // wave total
    int base = 0;
    if (lane == 63) base = atomicAdd(cursor, total);
    base = __shfl(base, 63);
    if (n < N) {
        int s = base + x - d;           // exclusive prefix within wave
        start[n] = s;
        cur[n] = s;
    }
}

__global__ __launch_bounds__(256) void k_fill(const int* __restrict__ src, const int* __restrict__ dst,
                                              int* __restrict__ cur, int* __restrict__ eidx, int E) {
    int e = blockIdx.x * 256 + threadIdx.x;
    if (e < E) {
        int p = atomicAdd(&cur[dst[e]], 1);
        eidx[p] = src[e];
    }
}

// ---------------- aggregation: agg[n,:] = sum over in-edges of h[src,:] ----------------
// one 64-lane wave per node; lane covers 2 floats (float2) of the 128-wide row.
// Edge indices are loaded 64-at-a-time coalesced, then shfl-broadcast; gather
// loads unrolled x4 for MLP.
__global__ __launch_bounds__(256) void k_agg(const float* __restrict__ h, const int* __restrict__ start,
                                             const int* __restrict__ deg, const int* __restrict__ eidx,
                                             float* __restrict__ agg, int N) {
    int w = blockIdx.x * 4 + (threadIdx.x >> 6);
    if (w >= N) return;
    int lane = threadIdx.x & 63;
    int s = start[w];
    int d = deg[w];
    const float2* h2 = (const float2*)h;
    float2 acc = make_float2(0.f, 0.f);
    int e = 0;
    while (e < d) {
        int nb = min(64, d - e);
        int myidx = (lane < nb) ? eidx[s + e + lane] : 0;   // one coalesced batch load
        int j = 0;
        for (; j + 4 <= nb; j += 4) {
            int i0 = __shfl(myidx, j + 0);
            int i1 = __shfl(myidx, j + 1);
            int i2 = __shfl(myidx, j + 2);
            int i3 = __shfl(myidx, j + 3);
            float2 v0 = h2[(size_t)i0 * 64 + lane];
            float2 v1 = h2[(size_t)i1 * 64 + lane];
            float2 v2 = h2[(size_t)i2 * 64 + lane];
            float2 v3 = h2[(size_t)i3 * 64 + lane];
            acc.x += v0.x + v1.x + v2.x + v3.x;
            acc.y += v0.y + v1.y + v2.y + v3.y;
        }
        for (; j < nb; ++j) {
            int i0 = __shfl(myidx, j);
            float2 v = h2[(size_t)i0 * 64 + lane];
            acc.x += v.x;
            acc.y += v.y;
        }
        e += nb;
    }
    ((float2*)agg)[(size_t)w * 64 + lane] = acc;
}

// ---------------- fused conv: hout = relu(agg @ Wr^T + br + hin @ Wroot^T) ----------------
// block: 256 threads -> 64 rows x 128 cols tile; thread: 8 rows x 4 cols.
// 8 rows/thread amortizes sB LDS reads 2x vs the 4-row version (was LDS-bound).
// NOTE: hout may alias agg (block reads only its own rows; stores after all reads).
__device__ inline void fma4(float4& a, float s, const float4& v) {
    a.x += s * v.x; a.y += s * v.y; a.z += s * v.z; a.w += s * v.w;
}

__global__ __launch_bounds__(256) void k_conv(const float* agg, const float* __restrict__ hin,
                                              const float* __restrict__ Wr, const float* __restrict__ br,
                                              const float* __restrict__ Wroot, float* hout, int N) {
    __shared__ float sA[2][64][32];     // [agg|h][row][k]  16 KB
    __shared__ float sB[2][32][128];    // [Wr|Wroot][k][j] 32 KB (transposed for j-contig reads)
    int tid = threadIdx.x;
    int n0 = blockIdx.x * 64;
    int jg = tid & 31;                  // j0 = jg*4
    int rg = tid >> 5;                  // r0 = rg*8  (0..7)

    float4 acc[8];
    #pragma unroll
    for (int r = 0; r < 8; ++r) acc[r] = make_float4(0.f, 0.f, 0.f, 0.f);

    for (int kc = 0; kc < HD; kc += 32) {
        // ---- stage A tiles (64 rows x 32 k, both matrices): 16 floats/thread ----
        {
            int ar = tid >> 2;            // 0..63
            int ak = (tid & 3) * 8;       // 0,8,16,24
            int an = n0 + ar;
            float4 a0 = make_float4(0.f, 0.f, 0.f, 0.f), a1 = a0, h0 = a0, h1 = a0;
            if (an < N) {
                a0 = *(const float4*)&agg[(size_t)an * HD + kc + ak];
                a1 = *(const float4*)&agg[(size_t)an * HD + kc + ak + 4];
                h0 = *(const float4*)&hin[(size_t)an * HD + kc + ak];
                h1 = *(const float4*)&hin[(size_t)an * HD + kc + ak + 4];
            }
            *(float4*)&sA[0][ar][ak]     = a0;
            *(float4*)&sA[0][ar][ak + 4] = a1;
            *(float4*)&sA[1][ar][ak]     = h0;
            *(float4*)&sA[1][ar][ak + 4] = h1;
        }
        // ---- stage B tiles transposed: sB[m][k][j] ----
        {
            int bj = tid & 127;
            int kh = (tid >> 7) * 16;
            #pragma unroll
            for (int m = 0; m < 2; ++m) {
                const float* W = m ? Wroot : Wr;
                #pragma unroll
                for (int q = 0; q < 4; ++q) {
                    float4 w = *(const float4*)&W[bj * HD + kc + kh + q * 4];
                    sB[m][kh + q * 4 + 0][bj] = w.x;
                    sB[m][kh + q * 4 + 1][bj] = w.y;
                    sB[m][kh + q * 4 + 2][bj] = w.z;
                    sB[m][kh + q * 4 + 3][bj] = w.w;
                }
            }
        }
        __syncthreads();
        // ---- compute ----
        #pragma unroll
        for (int kk = 0; kk < 32; kk += 4) {
            float4 wr[4], wo[4];
            #pragma unroll
            for (int q = 0; q < 4; ++q) {
                wr[q] = *(float4*)&sB[0][kk + q][jg * 4];
                wo[q] = *(float4*)&sB[1][kk + q][jg * 4];
            }
            #pragma unroll
            for (int r = 0; r < 8; ++r) {
                float4 a = *(float4*)&sA[0][rg * 8 + r][kk];
                float4 b = *(float4*)&sA[1][rg * 8 + r][kk];
                fma4(acc[r], a.x, wr[0]); fma4(acc[r], a.y, wr[1]);
                fma4(acc[r], a.z, wr[2]); fma4(acc[r], a.w, wr[3]);
                fma4(acc[r], b.x, wo[0]); fma4(acc[r], b.y, wo[1]);
                fma4(acc[r], b.z, wo[2]); fma4(acc[r], b.w, wo[3]);
            }
        }
        __syncthreads();
    }
    // ---- epilogue: bias + relu + store ----
    float4 bias = *(const float4*)&br[jg * 4];
    #pragma unroll
    for (int r = 0; r < 8; ++r) {
        int n = n0 + rg * 8 + r;
        if (n < N) {
            float4 v;
            v.x = fmaxf(acc[r].x + bias.x, 0.f);
            v.y = fmaxf(acc[r].y + bias.y, 0.f);
            v.z = fmaxf(acc[r].z + bias.z, 0.f);
            v.w = fmaxf(acc[r].w + bias.w, 0.f);
            *(float4*)&hout[(size_t)n * HD + jg * 4] = v;
        }
    }
}

// ---------------- pooling: emb[g,:] += run sums (batch is sorted) ----------------
// PCH=64: 782 blocks (was 98 @ PCH=512 -> 2% occupancy, 134us latency-bound)
#define PCH 64
__global__ __launch_bounds__(128) void k_pool(const float* __restrict__ h, const int* __restrict__ batch,
                                              float* __restrict__ emb, int* __restrict__ cnt, int N) {
    __shared__ int sb[PCH];
    int t = threadIdx.x;    // feature index 0..127
    int n0 = blockIdx.x * PCH;
    int nloc = min(PCH, N - n0);
    for (int i = t; i < nloc; i += 128) sb[i] = batch[n0 + i];
    __syncthreads();
    float run = 0.f;
    int runlen = 0;
    int gprev = sb[0];
    const float* hp = h + (size_t)n0 * HD + t;
    for (int i = 0; i < nloc; ++i) {
        int g = sb[i];
        if (g != gprev) {
            atomicAdd(&emb[gprev * HD + t], run);
            if (t == 0) atomicAdd(&cnt[gprev], runlen);
            run = 0.f; runlen = 0; gprev = g;
        }
        run += hp[(size_t)i * HD];
        runlen++;
    }
    atomicAdd(&emb[gprev * HD + t], run);
    if (t == 0) atomicAdd(&cnt[gprev], runlen);
}

// ---------------- final: out[g,c] = dot(emb[g]/max(cnt,1), lin_w[c]) + lin_b[c] ----------------
__global__ __launch_bounds__(128) void k_final(const float* __restrict__ emb, const int* __restrict__ cnt,
                                               const float* __restrict__ lw, const float* __restrict__ lb,
                                               float* __restrict__ out, int G) {
    int idx = blockIdx.x * 128 + threadIdx.x;
    if (idx >= G * CLS) return;
    int g = idx / CLS, c = idx % CLS;
    const float* e = emb + g * HD;
    const float* w = lw + c * HD;
    float s = 0.f;
    #pragma unroll
    for (int k = 0; k < HD; ++k) s += e[k] * w[k];
    float cc = fmaxf((float)cnt[g], 1.0f);
    out[idx] = s / cc + lb[c];
}

extern "C" void kernel_launch(void* const* d_in, const int* in_sizes, int n_in,
                              void* d_out, int out_size, void* d_ws, size_t ws_size,
                              hipStream_t stream) {
    const float* x     = (const float*)d_in[0];
    const int*   ei    = (const int*)d_in[1];
    const int*   batch = (const int*)d_in[2];
    const float* Wr[4]  = {(const float*)d_in[3], (const float*)d_in[6], (const float*)d_in[9],  (const float*)d_in[12]};
    const float* brl[4] = {(const float*)d_in[4], (const float*)d_in[7], (const float*)d_in[10], (const float*)d_in[13]};
    const float* Wo[4]  = {(const float*)d_in[5], (const float*)d_in[8], (const float*)d_in[11], (const float*)d_in[14]};
    const float* lw = (const float*)d_in[15];
    const float* lb = (const float*)d_in[16];
    float* out = (float*)d_out;

    int N = in_sizes[0] / HD;
    int E = in_sizes[1] / 2;
    int G = out_size / CLS;
    const int* src = ei;
    const int* dst = ei + E;

    // ---- workspace layout (zero-needed regions first, contiguous) ----
    char* ws = (char*)d_ws;
    size_t off = 0;
    auto alloc = [&](size_t bytes) -> char* {
        char* p = ws + off;
        off += (bytes + 255) & ~(size_t)255;
        return p;
    };
    int*   deg    = (int*)alloc((size_t)N * 4);        // zeroed
    int*   cursor = (int*)alloc(16);                   // zeroed
    float* emb    = (float*)alloc((size_t)G * HD * 4); // zeroed
    int*   cnt    = (int*)alloc((size_t)G * 4);        // zeroed
    size_t zero_bytes = off;
    int*   startp = (int*)alloc((size_t)N * 4);
    int*   curp   = (int*)alloc((size_t)N * 4);
    int*   eidx   = (int*)alloc((size_t)E * 4);
    float* bufA   = (float*)alloc((size_t)N * HD * 4);
    float* bufB   = (float*)alloc((size_t)N * HD * 4);

    hipMemsetAsync(d_ws, 0, zero_bytes, stream);

    // ---- CSR build ----
    k_deg<<<(E + 255) / 256, 256, 0, stream>>>(dst, deg, E);
    k_alloc<<<(N + 255) / 256, 256, 0, stream>>>(deg, startp, curp, cursor, N);
    k_fill<<<(E + 255) / 256, 256, 0, stream>>>(src, dst, curp, eidx, E);

    // ---- 4 GraphConv layers ----
    const float* hin = x;
    for (int l = 0; l < 4; ++l) {
        float* dbuf = (l & 1) ? bufB : bufA;
        k_agg<<<(N + 3) / 4, 256, 0, stream>>>(hin, startp, deg, eidx, dbuf, N);
        k_conv<<<(N + 63) / 64, 256, 0, stream>>>(dbuf, hin, Wr[l], brl[l], Wo[l], dbuf, N);
        hin = dbuf;
    }

    // ---- pooling + final linear ----
    k_pool<<<(N + PCH - 1) / PCH, 128, 0, stream>>>(hin, batch, emb, cnt, N);
    k_final<<<(G * CLS + 127) / 128, 128, 0, stream>>>(emb, cnt, lw, lb, out, G);
}

// Round 3
// 413.263 us; speedup vs baseline: 2.1382x; 1.6861x over previous
//
#include <hip/hip_runtime.h>

#define HD 128      // hidden / feature dim
#define CLS 10      // num classes

typedef __attribute__((ext_vector_type(8))) short bf16x8;
typedef __attribute__((ext_vector_type(4))) float floatx4;

// ---- bf16 helpers (manual, RNE) ----
__device__ inline unsigned short f2bf(float f) {
    unsigned u = __float_as_uint(f);
    return (unsigned short)((u + 0x7fffu + ((u >> 16) & 1u)) >> 16);
}
__device__ inline float bflo(unsigned u) { return __uint_as_float(u << 16); }
__device__ inline float bfhi(unsigned u) { return __uint_as_float(u & 0xffff0000u); }

// ---------------- CSR build ----------------
__global__ __launch_bounds__(256) void k_deg(const int* __restrict__ dst, int* __restrict__ deg, int E) {
    int e = blockIdx.x * 256 + threadIdx.x;
    if (e < E) atomicAdd(&deg[dst[e]], 1);
}

__global__ __launch_bounds__(256) void k_alloc(const int* __restrict__ deg, int* __restrict__ start,
                                               int* __restrict__ cur, int* __restrict__ cursor, int N) {
    int n = blockIdx.x * 256 + threadIdx.x;
    int lane = threadIdx.x & 63;
    int d = (n < N) ? deg[n] : 0;
    int x = d;
    #pragma unroll
    for (int off = 1; off < 64; off <<= 1) {
        int y = __shfl_up(x, off);
        if (lane >= off) x += y;
    }
    int total = __shfl(x, 63);
    int base = 0;
    if (lane == 63) base = atomicAdd(cursor, total);
    base = __shfl(base, 63);
    if (n < N) {
        int s = base + x - d;
        start[n] = s;
        cur[n] = s;
    }
}

__global__ __launch_bounds__(256) void k_fill(const int* __restrict__ src, const int* __restrict__ dst,
                                              int* __restrict__ cur, int* __restrict__ eidx, int E) {
    int e = blockIdx.x * 256 + threadIdx.x;
    if (e < E) {
        int p = atomicAdd(&cur[dst[e]], 1);
        eidx[p] = src[e];
    }
}

// ---------------- converts ----------------
__global__ __launch_bounds__(256) void k_cvt_x(const float* __restrict__ x, unsigned short* __restrict__ h, int total4) {
    int i = blockIdx.x * 256 + threadIdx.x;
    if (i >= total4) return;
    float4 v = ((const float4*)x)[i];
    ushort4 o;
    o.x = f2bf(v.x); o.y = f2bf(v.y); o.z = f2bf(v.z); o.w = f2bf(v.w);
    ((ushort4*)h)[i] = o;
}

// Wcat[layer][j][k] bf16, k<128 -> Wr[j][k], else Wroot[j][k-128]
__global__ __launch_bounds__(256) void k_cvt_w(const float* Wr0, const float* Wo0, const float* Wr1, const float* Wo1,
                                               const float* Wr2, const float* Wo2, const float* Wr3, const float* Wo3,
                                               unsigned short* __restrict__ Wcat) {
    int l = blockIdx.y;
    const float* Wr = (l == 0) ? Wr0 : (l == 1) ? Wr1 : (l == 2) ? Wr2 : Wr3;
    const float* Wo = (l == 0) ? Wo0 : (l == 1) ? Wo1 : (l == 2) ? Wo2 : Wo3;
    int idx = blockIdx.x * 256 + threadIdx.x;      // 0..32767
    int j = idx >> 8, k = idx & 255;
    float v = (k < 128) ? Wr[j * 128 + k] : Wo[j * 128 + (k - 128)];
    Wcat[(size_t)l * 32768 + idx] = f2bf(v);
}

// ---------------- aggregation (bf16 rows): agg[n,:] = sum over in-edges of h[src,:] ----------------
// one 64-lane wave per node; lane covers one uint (2 bf16) of the 256B row
__global__ __launch_bounds__(256) void k_agg(const unsigned short* __restrict__ h, const int* __restrict__ start,
                                             const int* __restrict__ deg, const int* __restrict__ eidx,
                                             unsigned short* __restrict__ agg, int N) {
    int w = blockIdx.x * 4 + (threadIdx.x >> 6);
    if (w >= N) return;
    int lane = threadIdx.x & 63;
    int s = start[w];
    int d = deg[w];
    const unsigned* h2 = (const unsigned*)h;
    float ax = 0.f, ay = 0.f;
    int e = 0;
    while (e < d) {
        int nb = min(64, d - e);
        int myidx = (lane < nb) ? eidx[s + e + lane] : 0;
        int j = 0;
        for (; j + 4 <= nb; j += 4) {
            int i0 = __shfl(myidx, j + 0);
            int i1 = __shfl(myidx, j + 1);
            int i2 = __shfl(myidx, j + 2);
            int i3 = __shfl(myidx, j + 3);
            unsigned u0 = h2[(size_t)i0 * 64 + lane];
            unsigned u1 = h2[(size_t)i1 * 64 + lane];
            unsigned u2 = h2[(size_t)i2 * 64 + lane];
            unsigned u3 = h2[(size_t)i3 * 64 + lane];
            ax += bflo(u0) + bflo(u1) + bflo(u2) + bflo(u3);
            ay += bfhi(u0) + bfhi(u1) + bfhi(u2) + bfhi(u3);
        }
        for (; j < nb; ++j) {
            int i0 = __shfl(myidx, j);
            unsigned u = h2[(size_t)i0 * 64 + lane];
            ax += bflo(u);
            ay += bfhi(u);
        }
        e += nb;
    }
    unsigned o = (unsigned)f2bf(ax) | ((unsigned)f2bf(ay) << 16);
    ((unsigned*)agg)[(size_t)w * 64 + lane] = o;
}

// ---------------- fused conv via MFMA: hout = relu([agg|hin] @ Wcat^T + br) ----------------
// block 256 thr = 4 waves (2x2), block tile 128 rows x 128 cols, wave tile 64x64.
// K = 256 (k<128 from agg, k>=128 from hin), 8 k-steps of 32.
// mfma_f32_16x16x32_bf16: A[m=lane&15][k=quad*8+j]; B[k=quad*8+j][n=lane&15]; C col=lane&15,row=quad*4+reg.
__global__ __launch_bounds__(256) void k_conv(const unsigned short* __restrict__ agg, const unsigned short* __restrict__ hin,
                                              const unsigned short* __restrict__ Wcat, const float* __restrict__ br,
                                              unsigned short* __restrict__ hout, int N) {
    __shared__ unsigned short sA[128][40];   // rows x 32k (+8 pad), 80B row stride
    __shared__ unsigned short sB[128][40];   // cols x 32k (+8 pad)
    int tid = threadIdx.x;
    int wave = tid >> 6, lane = tid & 63;
    int wr = wave >> 1, wc = wave & 1;
    int m0 = wr * 64, n0 = wc * 64;
    int lm = lane & 15, quad = lane >> 4;
    int nbase = blockIdx.x * 128;

    floatx4 acc[4][4];
    #pragma unroll
    for (int mt = 0; mt < 4; ++mt)
        #pragma unroll
        for (int nt = 0; nt < 4; ++nt)
            acc[mt][nt] = {0.f, 0.f, 0.f, 0.f};

    int r = tid >> 1;          // staging row 0..127
    int p = tid & 1;           // 16-elem half of the 32-elem slice

    for (int s = 0; s < 8; ++s) {
        // ---- stage A (128 rows x 32 k bf16) ----
        const unsigned short* srcA = (s < 4) ? agg : hin;
        int koff = (s & 3) * 32;
        const unsigned short* ga = srcA + (size_t)(nbase + r) * HD + koff + p * 16;
        *(uint4*)&sA[r][p * 16]     = *(const uint4*)ga;
        *(uint4*)&sA[r][p * 16 + 8] = *(const uint4*)(ga + 8);
        // ---- stage B (128 cols x 32 k bf16) ----
        const unsigned short* gb = Wcat + (size_t)r * 256 + s * 32 + p * 16;
        *(uint4*)&sB[r][p * 16]     = *(const uint4*)gb;
        *(uint4*)&sB[r][p * 16 + 8] = *(const uint4*)(gb + 8);
        __syncthreads();
        // ---- fragments + MFMA ----
        bf16x8 af[4], bfr[4];
        #pragma unroll
        for (int mt = 0; mt < 4; ++mt) af[mt]  = *(const bf16x8*)&sA[m0 + mt * 16 + lm][quad * 8];
        #pragma unroll
        for (int nt = 0; nt < 4; ++nt) bfr[nt] = *(const bf16x8*)&sB[n0 + nt * 16 + lm][quad * 8];
        #pragma unroll
        for (int mt = 0; mt < 4; ++mt)
            #pragma unroll
            for (int nt = 0; nt < 4; ++nt)
                acc[mt][nt] = __builtin_amdgcn_mfma_f32_16x16x32_bf16(af[mt], bfr[nt], acc[mt][nt], 0, 0, 0);
        __syncthreads();
    }

    // ---- epilogue: bias + relu + bf16 store ----
    #pragma unroll
    for (int nt = 0; nt < 4; ++nt) {
        int col = n0 + nt * 16 + lm;
        float bias = br[col];
        #pragma unroll
        for (int mt = 0; mt < 4; ++mt) {
            int row0 = nbase + m0 + mt * 16 + quad * 4;
            #pragma unroll
            for (int reg = 0; reg < 4; ++reg) {
                int rr = row0 + reg;
                if (rr < N) {
                    float v = fmaxf(acc[mt][nt][reg] + bias, 0.f);
                    hout[(size_t)rr * HD + col] = f2bf(v);
                }
            }
        }
    }
}

// ---------------- pooling: emb[g,:] += run sums (batch sorted); bf16 h, fp32 emb ----------------
#define PCH 32
__global__ __launch_bounds__(64) void k_pool(const unsigned short* __restrict__ h, const int* __restrict__ batch,
                                             float* __restrict__ emb, int* __restrict__ cnt, int N) {
    int t = threadIdx.x;        // uint column 0..63 (2 features)
    int n0 = blockIdx.x * PCH;
    int nloc = min(PCH, N - n0);
    const unsigned* h2 = (const unsigned*)h;
    float rx = 0.f, ry = 0.f;
    int runlen = 0;
    int gprev = batch[n0];
    for (int i = 0; i < nloc; ++i) {
        int g = batch[n0 + i];
        if (g != gprev) {
            atomicAdd(&emb[gprev * HD + 2 * t], rx);
            atomicAdd(&emb[gprev * HD + 2 * t + 1], ry);
            if (t == 0) atomicAdd(&cnt[gprev], runlen);
            rx = ry = 0.f; runlen = 0; gprev = g;
        }
        unsigned u = h2[(size_t)(n0 + i) * 64 + t];
        rx += bflo(u);
        ry += bfhi(u);
        runlen++;
    }
    atomicAdd(&emb[gprev * HD + 2 * t], rx);
    atomicAdd(&emb[gprev * HD + 2 * t + 1], ry);
    if (t == 0) atomicAdd(&cnt[gprev], runlen);
}

// ---------------- final linear ----------------
__global__ __launch_bounds__(128) void k_final(const float* __restrict__ emb, const int* __restrict__ cnt,
                                               const float* __restrict__ lw, const float* __restrict__ lb,
                                               float* __restrict__ out, int G) {
    int idx = blockIdx.x * 128 + threadIdx.x;
    if (idx >= G * CLS) return;
    int g = idx / CLS, c = idx % CLS;
    const float* e = emb + g * HD;
    const float* w = lw + c * HD;
    float s = 0.f;
    #pragma unroll
    for (int k = 0; k < HD; ++k) s += e[k] * w[k];
    float cc = fmaxf((float)cnt[g], 1.0f);
    out[idx] = s / cc + lb[c];
}

extern "C" void kernel_launch(void* const* d_in, const int* in_sizes, int n_in,
                              void* d_out, int out_size, void* d_ws, size_t ws_size,
                              hipStream_t stream) {
    const float* x     = (const float*)d_in[0];
    const int*   ei    = (const int*)d_in[1];
    const int*   batch = (const int*)d_in[2];
    const float* Wr[4]  = {(const float*)d_in[3], (const float*)d_in[6], (const float*)d_in[9],  (const float*)d_in[12]};
    const float* brl[4] = {(const float*)d_in[4], (const float*)d_in[7], (const float*)d_in[10], (const float*)d_in[13]};
    const float* Wo[4]  = {(const float*)d_in[5], (const float*)d_in[8], (const float*)d_in[11], (const float*)d_in[14]};
    const float* lw = (const float*)d_in[15];
    const float* lb = (const float*)d_in[16];
    float* out = (float*)d_out;

    int N = in_sizes[0] / HD;
    int E = in_sizes[1] / 2;
    int G = out_size / CLS;
    int Np = (N + 127) & ~127;           // padded row count (conv reads full 128-row tiles)
    const int* src = ei;
    const int* dst = ei + E;

    // ---- workspace layout (zero-needed regions first) ----
    char* ws = (char*)d_ws;
    size_t off = 0;
    auto alloc = [&](size_t bytes) -> char* {
        char* p = ws + off;
        off += (bytes + 255) & ~(size_t)255;
        return p;
    };
    int*   deg    = (int*)alloc((size_t)N * 4);        // zeroed
    int*   cursor = (int*)alloc(16);                   // zeroed
    float* emb    = (float*)alloc((size_t)G * HD * 4); // zeroed
    int*   cnt    = (int*)alloc((size_t)G * 4);        // zeroed
    size_t zero_bytes = off;
    int*   startp = (int*)alloc((size_t)N * 4);
    int*   curp   = (int*)alloc((size_t)N * 4);
    int*   eidx   = (int*)alloc((size_t)E * 4);
    unsigned short* hbuf0 = (unsigned short*)alloc((size_t)Np * HD * 2);
    unsigned short* hbuf1 = (unsigned short*)alloc((size_t)Np * HD * 2);
    unsigned short* aggb  = (unsigned short*)alloc((size_t)Np * HD * 2);
    unsigned short* Wcat  = (unsigned short*)alloc((size_t)4 * 128 * 256 * 2);

    hipMemsetAsync(d_ws, 0, zero_bytes, stream);

    // ---- CSR build + converts ----
    k_deg<<<(E + 255) / 256, 256, 0, stream>>>(dst, deg, E);
    k_alloc<<<(N + 255) / 256, 256, 0, stream>>>(deg, startp, curp, cursor, N);
    k_fill<<<(E + 255) / 256, 256, 0, stream>>>(src, dst, curp, eidx, E);
    int total4 = N * HD / 4;
    k_cvt_x<<<(total4 + 255) / 256, 256, 0, stream>>>(x, hbuf0, total4);
    dim3 wgrid(128, 4);
    k_cvt_w<<<wgrid, 256, 0, stream>>>(Wr[0], Wo[0], Wr[1], Wo[1], Wr[2], Wo[2], Wr[3], Wo[3], Wcat);

    // ---- 4 GraphConv layers ----
    unsigned short* hcur = hbuf0;
    unsigned short* hnxt = hbuf1;
    for (int l = 0; l < 4; ++l) {
        k_agg<<<(N + 3) / 4, 256, 0, stream>>>(hcur, startp, deg, eidx, aggb, N);
        k_conv<<<Np / 128, 256, 0, stream>>>(aggb, hcur, Wcat + (size_t)l * 32768, brl[l], hnxt, N);
        unsigned short* t = hcur; hcur = hnxt; hnxt = t;
    }

    // ---- pooling + final linear ----
    k_pool<<<(N + PCH - 1) / PCH, 64, 0, stream>>>(hcur, batch, emb, cnt, N);
    k_final<<<(G * CLS + 127) / 128, 128, 0, stream>>>(emb, cnt, lw, lb, out, G);
}

// Round 4
// 353.593 us; speedup vs baseline: 2.4990x; 1.1688x over previous
//
#include <hip/hip_runtime.h>

#define HD 128      // hidden / feature dim
#define CLS 10      // num classes
#define BSH 7       // bucket shift: 128 nodes / bucket
#define TS 4096     // edges per scatter tile
#define FCAP 3072   // LDS capacity per bucket in k_fine (mean occupancy ~2046)

typedef __attribute__((ext_vector_type(8))) short bf16x8;
typedef __attribute__((ext_vector_type(4))) float floatx4;

// ---- bf16 helpers (manual, RNE) ----
__device__ inline unsigned short f2bf(float f) {
    unsigned u = __float_as_uint(f);
    return (unsigned short)((u + 0x7fffu + ((u >> 16) & 1u)) >> 16);
}
__device__ inline float bflo(unsigned u) { return __uint_as_float(u << 16); }
__device__ inline float bfhi(unsigned u) { return __uint_as_float(u & 0xffff0000u); }

// =============== CSR build via 2-level counting sort (no random scatter) ===============
// pass 1: per-tile histogram over coarse buckets (dst>>BSH)
__global__ __launch_bounds__(256) void k_hist(const int* __restrict__ dst, int* __restrict__ hist,
                                              int* __restrict__ total, int E, int NB, int NT) {
    __shared__ int lh[512];
    int t = blockIdx.x, tid = threadIdx.x;
    for (int b = tid; b < NB; b += 256) lh[b] = 0;
    __syncthreads();
    int e0 = t * TS;
    for (int i = tid; i < TS; i += 256) {
        int e = e0 + i;
        if (e < E) atomicAdd(&lh[dst[e] >> BSH], 1);
    }
    __syncthreads();
    for (int b = tid; b < NB; b += 256) {
        int c = lh[b];
        hist[b * NT + t] = c;
        if (c) atomicAdd(&total[b], c);
    }
}

// pass 2a: exclusive prefix over bucket totals -> base[b]
__global__ __launch_bounds__(512) void k_scan1(const int* __restrict__ total, int* __restrict__ base, int NB) {
    __shared__ int s[512];
    int tid = threadIdx.x;
    int own = (tid < NB) ? total[tid] : 0;
    s[tid] = own;
    __syncthreads();
    for (int d = 1; d < 512; d <<= 1) {
        int v = (tid >= d) ? s[tid - d] : 0;
        __syncthreads();
        s[tid] += v;
        __syncthreads();
    }
    if (tid < NB) base[tid] = s[tid] - own;
}

// pass 2b: per-bucket exclusive prefix over tiles -> off[b][t]
__global__ __launch_bounds__(256) void k_scan2(const int* __restrict__ hist, const int* __restrict__ base,
                                               int* __restrict__ off, int NT) {
    __shared__ int s[256];
    int b = blockIdx.x, tid = threadIdx.x;
    int own = (tid < NT) ? hist[b * NT + tid] : 0;
    s[tid] = own;
    __syncthreads();
    for (int d = 1; d < 256; d <<= 1) {
        int v = (tid >= d) ? s[tid - d] : 0;
        __syncthreads();
        s[tid] += v;
        __syncthreads();
    }
    if (tid < NT) off[b * NT + tid] = base[b] + s[tid] - own;
}

// pass 3: LDS counting-sort of each tile by bucket, contiguous run writes
__global__ __launch_bounds__(512) void k_scatter(const int* __restrict__ src, const int* __restrict__ dst,
                                                 const int* __restrict__ off, uint2* __restrict__ pairs,
                                                 int E, int NB, int NT) {
    __shared__ int lh[512];
    __shared__ int lp[512];
    __shared__ uint2 lpair[TS];
    int t = blockIdx.x, tid = threadIdx.x;
    lh[tid] = 0;
    __syncthreads();
    int e0 = t * TS;
    int sv[TS / 512], dv[TS / 512], rk[TS / 512];
    #pragma unroll
    for (int j = 0; j < TS / 512; ++j) {
        int e = e0 + j * 512 + tid;
        if (e < E) {
            int dd = dst[e];
            sv[j] = src[e];
            dv[j] = dd;
            rk[j] = atomicAdd(&lh[dd >> BSH], 1);
        } else dv[j] = -1;
    }
    __syncthreads();
    int own = lh[tid];
    lp[tid] = own;
    __syncthreads();
    for (int d = 1; d < 512; d <<= 1) {
        int v = (tid >= d) ? lp[tid - d] : 0;
        __syncthreads();
        lp[tid] += v;
        __syncthreads();
    }
    int excl = lp[tid] - own;
    __syncthreads();
    lh[tid] = excl;                      // lh now = exclusive prefix per bucket
    __syncthreads();
    #pragma unroll
    for (int j = 0; j < TS / 512; ++j) {
        if (dv[j] >= 0) {
            int pos = lh[dv[j] >> BSH] + rk[j];
            lpair[pos] = make_uint2((unsigned)sv[j], (unsigned)dv[j]);
        }
    }
    __syncthreads();
    for (int b = tid; b < NB; b += 512) lp[b] = off[b * NT + t];   // preload off column
    __syncthreads();
    int nloc = min(TS, E - e0);
    for (int i = tid; i < nloc; i += 512) {
        uint2 p = lpair[i];
        int b = (int)(p.y >> BSH);
        pairs[lp[b] + (i - lh[b])] = p;  // contiguous runs per bucket
    }
}

// pass 4: per-bucket exact sort -> eidx, deg, start
__global__ __launch_bounds__(256) void k_fine(const uint2* __restrict__ pairs, const int* __restrict__ base,
                                              const int* __restrict__ total, int* __restrict__ eidx,
                                              int* __restrict__ deg, int* __restrict__ start, int N) {
    __shared__ int cnt[128], pref[128];
    __shared__ int ssrc[FCAP];
    __shared__ unsigned short sln[FCAP], srk[FCAP];
    int b = blockIdx.x, tid = threadIdx.x;
    int n0 = b << BSH;
    int nn = min(128, N - n0);
    int eb = base[b];
    int ec = min(total[b], FCAP);
    if (tid < 128) cnt[tid] = 0;
    __syncthreads();
    for (int i = tid; i < ec; i += 256) {
        uint2 p = pairs[eb + i];
        int ln = (int)p.y - n0;
        int r = atomicAdd(&cnt[ln], 1);
        ssrc[i] = (int)p.x;
        sln[i] = (unsigned short)ln;
        srk[i] = (unsigned short)r;
    }
    __syncthreads();
    if (tid < 128) pref[tid] = cnt[tid];
    __syncthreads();
    for (int d = 1; d < 128; d <<= 1) {
        int v = 0;
        if (tid < 128 && tid >= d) v = pref[tid - d];
        __syncthreads();
        if (tid < 128) pref[tid] += v;
        __syncthreads();
    }
    if (tid < nn) {
        deg[n0 + tid] = cnt[tid];
        start[n0 + tid] = eb + pref[tid] - cnt[tid];
    }
    for (int i = tid; i < ec; i += 256) {
        int ln = sln[i];
        int pos = pref[ln] - cnt[ln] + srk[i];
        eidx[eb + pos] = ssrc[i];        // block-local burst, L2-combined
    }
}

// ---------------- converts ----------------
__global__ __launch_bounds__(256) void k_cvt_x(const float* __restrict__ x, unsigned short* __restrict__ h, int total4) {
    int i = blockIdx.x * 256 + threadIdx.x;
    if (i >= total4) return;
    float4 v = ((const float4*)x)[i];
    ushort4 o;
    o.x = f2bf(v.x); o.y = f2bf(v.y); o.z = f2bf(v.z); o.w = f2bf(v.w);
    ((ushort4*)h)[i] = o;
}

__global__ __launch_bounds__(256) void k_cvt_w(const float* Wr0, const float* Wo0, const float* Wr1, const float* Wo1,
                                               const float* Wr2, const float* Wo2, const float* Wr3, const float* Wo3,
                                               unsigned short* __restrict__ Wcat) {
    int l = blockIdx.y;
    const float* Wr = (l == 0) ? Wr0 : (l == 1) ? Wr1 : (l == 2) ? Wr2 : Wr3;
    const float* Wo = (l == 0) ? Wo0 : (l == 1) ? Wo1 : (l == 2) ? Wo2 : Wo3;
    int idx = blockIdx.x * 256 + threadIdx.x;
    int j = idx >> 8, k = idx & 255;
    float v = (k < 128) ? Wr[j * 128 + k] : Wo[j * 128 + (k - 128)];
    Wcat[(size_t)l * 32768 + idx] = f2bf(v);
}

// ---------------- aggregation (bf16 rows), 8 gathers in flight ----------------
__global__ __launch_bounds__(256) void k_agg(const unsigned short* __restrict__ h, const int* __restrict__ start,
                                             const int* __restrict__ deg, const int* __restrict__ eidx,
                                             unsigned short* __restrict__ agg, int N) {
    int w = blockIdx.x * 4 + (threadIdx.x >> 6);
    if (w >= N) return;
    int lane = threadIdx.x & 63;
    int s = start[w];
    int d = deg[w];
    const unsigned* h2 = (const unsigned*)h;
    float ax = 0.f, ay = 0.f;
    int e = 0;
    while (e < d) {
        int nb = min(64, d - e);
        int myidx = (lane < nb) ? eidx[s + e + lane] : 0;
        int j = 0;
        for (; j + 8 <= nb; j += 8) {
            unsigned u[8];
            #pragma unroll
            for (int q = 0; q < 8; ++q) {
                int iq = __shfl(myidx, j + q);
                u[q] = h2[(size_t)iq * 64 + lane];
            }
            #pragma unroll
            for (int q = 0; q < 8; ++q) { ax += bflo(u[q]); ay += bfhi(u[q]); }
        }
        for (; j < nb; ++j) {
            int i0 = __shfl(myidx, j);
            unsigned u = h2[(size_t)i0 * 64 + lane];
            ax += bflo(u);
            ay += bfhi(u);
        }
        e += nb;
    }
    unsigned o = (unsigned)f2bf(ax) | ((unsigned)f2bf(ay) << 16);
    ((unsigned*)agg)[(size_t)w * 64 + lane] = o;
}

// ---------------- fused conv via MFMA: hout = relu([agg|hin] @ Wcat^T + br) ----------------
__global__ __launch_bounds__(256) void k_conv(const unsigned short* __restrict__ agg, const unsigned short* __restrict__ hin,
                                              const unsigned short* __restrict__ Wcat, const float* __restrict__ br,
                                              unsigned short* __restrict__ hout, int N) {
    __shared__ unsigned short sA[128][40];
    __shared__ unsigned short sB[128][40];
    int tid = threadIdx.x;
    int wave = tid >> 6, lane = tid & 63;
    int wr = wave >> 1, wc = wave & 1;
    int m0 = wr * 64, n0 = wc * 64;
    int lm = lane & 15, quad = lane >> 4;
    int nbase = blockIdx.x * 128;

    floatx4 acc[4][4];
    #pragma unroll
    for (int mt = 0; mt < 4; ++mt)
        #pragma unroll
        for (int nt = 0; nt < 4; ++nt)
            acc[mt][nt] = {0.f, 0.f, 0.f, 0.f};

    int r = tid >> 1;
    int p = tid & 1;

    for (int s = 0; s < 8; ++s) {
        const unsigned short* srcA = (s < 4) ? agg : hin;
        int koff = (s & 3) * 32;
        const unsigned short* ga = srcA + (size_t)(nbase + r) * HD + koff + p * 16;
        *(uint4*)&sA[r][p * 16]     = *(const uint4*)ga;
        *(uint4*)&sA[r][p * 16 + 8] = *(const uint4*)(ga + 8);
        const unsigned short* gb = Wcat + (size_t)r * 256 + s * 32 + p * 16;
        *(uint4*)&sB[r][p * 16]     = *(const uint4*)gb;
        *(uint4*)&sB[r][p * 16 + 8] = *(const uint4*)(gb + 8);
        __syncthreads();
        bf16x8 af[4], bfr[4];
        #pragma unroll
        for (int mt = 0; mt < 4; ++mt) af[mt]  = *(const bf16x8*)&sA[m0 + mt * 16 + lm][quad * 8];
        #pragma unroll
        for (int nt = 0; nt < 4; ++nt) bfr[nt] = *(const bf16x8*)&sB[n0 + nt * 16 + lm][quad * 8];
        #pragma unroll
        for (int mt = 0; mt < 4; ++mt)
            #pragma unroll
            for (int nt = 0; nt < 4; ++nt)
                acc[mt][nt] = __builtin_amdgcn_mfma_f32_16x16x32_bf16(af[mt], bfr[nt], acc[mt][nt], 0, 0, 0);
        __syncthreads();
    }

    #pragma unroll
    for (int nt = 0; nt < 4; ++nt) {
        int col = n0 + nt * 16 + lm;
        float bias = br[col];
        #pragma unroll
        for (int mt = 0; mt < 4; ++mt) {
            int row0 = nbase + m0 + mt * 16 + quad * 4;
            #pragma unroll
            for (int reg = 0; reg < 4; ++reg) {
                int rr = row0 + reg;
                if (rr < N) {
                    float v = fmaxf(acc[mt][nt][reg] + bias, 0.f);
                    hout[(size_t)rr * HD + col] = f2bf(v);
                }
            }
        }
    }
}

// ---------------- pooling ----------------
#define PCH 32
__global__ __launch_bounds__(64) void k_pool(const unsigned short* __restrict__ h, const int* __restrict__ batch,
                                             float* __restrict__ emb, int* __restrict__ cnt, int N) {
    int t = threadIdx.x;
    int n0 = blockIdx.x * PCH;
    int nloc = min(PCH, N - n0);
    const unsigned* h2 = (const unsigned*)h;
    float rx = 0.f, ry = 0.f;
    int runlen = 0;
    int gprev = batch[n0];
    for (int i = 0; i < nloc; ++i) {
        int g = batch[n0 + i];
        if (g != gprev) {
            atomicAdd(&emb[gprev * HD + 2 * t], rx);
            atomicAdd(&emb[gprev * HD + 2 * t + 1], ry);
            if (t == 0) atomicAdd(&cnt[gprev], runlen);
            rx = ry = 0.f; runlen = 0; gprev = g;
        }
        unsigned u = h2[(size_t)(n0 + i) * 64 + t];
        rx += bflo(u);
        ry += bfhi(u);
        runlen++;
    }
    atomicAdd(&emb[gprev * HD + 2 * t], rx);
    atomicAdd(&emb[gprev * HD + 2 * t + 1], ry);
    if (t == 0) atomicAdd(&cnt[gprev], runlen);
}

// ---------------- final linear ----------------
__global__ __launch_bounds__(128) void k_final(const float* __restrict__ emb, const int* __restrict__ cnt,
                                               const float* __restrict__ lw, const float* __restrict__ lb,
                                               float* __restrict__ out, int G) {
    int idx = blockIdx.x * 128 + threadIdx.x;
    if (idx >= G * CLS) return;
    int g = idx / CLS, c = idx % CLS;
    const float* e = emb + g * HD;
    const float* w = lw + c * HD;
    float s = 0.f;
    #pragma unroll
    for (int k = 0; k < HD; ++k) s += e[k] * w[k];
    float cc = fmaxf((float)cnt[g], 1.0f);
    out[idx] = s / cc + lb[c];
}

extern "C" void kernel_launch(void* const* d_in, const int* in_sizes, int n_in,
                              void* d_out, int out_size, void* d_ws, size_t ws_size,
                              hipStream_t stream) {
    const float* x     = (const float*)d_in[0];
    const int*   ei    = (const int*)d_in[1];
    const int*   batch = (const int*)d_in[2];
    const float* Wr[4]  = {(const float*)d_in[3], (const float*)d_in[6], (const float*)d_in[9],  (const float*)d_in[12]};
    const float* brl[4] = {(const float*)d_in[4], (const float*)d_in[7], (const float*)d_in[10], (const float*)d_in[13]};
    const float* Wo[4]  = {(const float*)d_in[5], (const float*)d_in[8], (const float*)d_in[11], (const float*)d_in[14]};
    const float* lw = (const float*)d_in[15];
    const float* lb = (const float*)d_in[16];
    float* out = (float*)d_out;

    int N = in_sizes[0] / HD;
    int E = in_sizes[1] / 2;
    int G = out_size / CLS;
    int Np = (N + 127) & ~127;
    int NB = (N + 127) >> 7;            // coarse buckets (<=512)
    int NT = (E + TS - 1) / TS;         // tiles (<=256)
    const int* src = ei;
    const int* dst = ei + E;

    // ---- workspace layout (zero-needed regions first) ----
    char* ws = (char*)d_ws;
    size_t off_b = 0;
    auto alloc = [&](size_t bytes) -> char* {
        char* p = ws + off_b;
        off_b += (bytes + 255) & ~(size_t)255;
        return p;
    };
    int*   total  = (int*)alloc((size_t)NB * 4);       // zeroed
    float* emb    = (float*)alloc((size_t)G * HD * 4); // zeroed
    int*   cnt    = (int*)alloc((size_t)G * 4);        // zeroed
    size_t zero_bytes = off_b;
    int*   base   = (int*)alloc((size_t)NB * 4);
    int*   hist   = (int*)alloc((size_t)NB * NT * 4);
    int*   offv   = (int*)alloc((size_t)NB * NT * 4);
    uint2* pairs  = (uint2*)alloc((size_t)E * 8);
    int*   eidx   = (int*)alloc((size_t)E * 4);
    int*   deg    = (int*)alloc((size_t)N * 4);
    int*   startp = (int*)alloc((size_t)N * 4);
    unsigned short* hbuf0 = (unsigned short*)alloc((size_t)Np * HD * 2);
    unsigned short* hbuf1 = (unsigned short*)alloc((size_t)Np * HD * 2);
    unsigned short* aggb  = (unsigned short*)alloc((size_t)Np * HD * 2);
    unsigned short* Wcat  = (unsigned short*)alloc((size_t)4 * 128 * 256 * 2);

    hipMemsetAsync(d_ws, 0, zero_bytes, stream);

    // ---- CSR build (counting sort) ----
    k_hist<<<NT, 256, 0, stream>>>(dst, hist, total, E, NB, NT);
    k_scan1<<<1, 512, 0, stream>>>(total, base, NB);
    k_scan2<<<NB, 256, 0, stream>>>(hist, base, offv, NT);
    k_scatter<<<NT, 512, 0, stream>>>(src, dst, offv, pairs, E, NB, NT);
    k_fine<<<NB, 256, 0, stream>>>(pairs, base, total, eidx, deg, startp, N);

    // ---- converts ----
    int total4 = N * HD / 4;
    k_cvt_x<<<(total4 + 255) / 256, 256, 0, stream>>>(x, hbuf0, total4);
    dim3 wgrid(128, 4);
    k_cvt_w<<<wgrid, 256, 0, stream>>>(Wr[0], Wo[0], Wr[1], Wo[1], Wr[2], Wo[2], Wr[3], Wo[3], Wcat);

    // ---- 4 GraphConv layers ----
    unsigned short* hcur = hbuf0;
    unsigned short* hnxt = hbuf1;
    for (int l = 0; l < 4; ++l) {
        k_agg<<<(N + 3) / 4, 256, 0, stream>>>(hcur, startp, deg, eidx, aggb, N);
        k_conv<<<Np / 128, 256, 0, stream>>>(aggb, hcur, Wcat + (size_t)l * 32768, brl[l], hnxt, N);
        unsigned short* t = hcur; hcur = hnxt; hnxt = t;
    }

    // ---- pooling + final linear ----
    k_pool<<<(N + PCH - 1) / PCH, 64, 0, stream>>>(hcur, batch, emb, cnt, N);
    k_final<<<(G * CLS + 127) / 128, 128, 0, stream>>>(emb, cnt, lw, lb, out, G);
}

// Round 5
// 340.070 us; speedup vs baseline: 2.5983x; 1.0398x over previous
//
#include <hip/hip_runtime.h>

#define HD 128      // hidden / feature dim
#define CLS 10      // num classes
#define BSH 7       // bucket shift: 128 nodes / bucket
#define TS 4096     // edges per scatter tile
#define FCAP 3072   // LDS capacity per bucket in k_fine (mean occupancy ~2046)

typedef __attribute__((ext_vector_type(8))) short bf16x8;
typedef __attribute__((ext_vector_type(4))) float floatx4;

// ---- bf16 helpers (manual, RNE) ----
__device__ inline unsigned short f2bf(float f) {
    unsigned u = __float_as_uint(f);
    return (unsigned short)((u + 0x7fffu + ((u >> 16) & 1u)) >> 16);
}
__device__ inline float bflo(unsigned u) { return __uint_as_float(u << 16); }
__device__ inline float bfhi(unsigned u) { return __uint_as_float(u & 0xffff0000u); }

// =============== CSR build via 2-level counting sort (no random scatter) ===============
__global__ __launch_bounds__(256) void k_hist(const int* __restrict__ dst, int* __restrict__ hist,
                                              int* __restrict__ total, int E, int NB, int NT) {
    __shared__ int lh[512];
    int t = blockIdx.x, tid = threadIdx.x;
    for (int b = tid; b < NB; b += 256) lh[b] = 0;
    __syncthreads();
    int e0 = t * TS;
    for (int i = tid; i < TS; i += 256) {
        int e = e0 + i;
        if (e < E) atomicAdd(&lh[dst[e] >> BSH], 1);
    }
    __syncthreads();
    for (int b = tid; b < NB; b += 256) {
        int c = lh[b];
        hist[b * NT + t] = c;
        if (c) atomicAdd(&total[b], c);
    }
}

__global__ __launch_bounds__(512) void k_scan1(const int* __restrict__ total, int* __restrict__ base, int NB) {
    __shared__ int s[512];
    int tid = threadIdx.x;
    int own = (tid < NB) ? total[tid] : 0;
    s[tid] = own;
    __syncthreads();
    for (int d = 1; d < 512; d <<= 1) {
        int v = (tid >= d) ? s[tid - d] : 0;
        __syncthreads();
        s[tid] += v;
        __syncthreads();
    }
    if (tid < NB) base[tid] = s[tid] - own;
}

__global__ __launch_bounds__(256) void k_scan2(const int* __restrict__ hist, const int* __restrict__ base,
                                               int* __restrict__ off, int NT) {
    __shared__ int s[256];
    int b = blockIdx.x, tid = threadIdx.x;
    int own = (tid < NT) ? hist[b * NT + tid] : 0;
    s[tid] = own;
    __syncthreads();
    for (int d = 1; d < 256; d <<= 1) {
        int v = (tid >= d) ? s[tid - d] : 0;
        __syncthreads();
        s[tid] += v;
        __syncthreads();
    }
    if (tid < NT) off[b * NT + tid] = base[b] + s[tid] - own;
}

__global__ __launch_bounds__(512) void k_scatter(const int* __restrict__ src, const int* __restrict__ dst,
                                                 const int* __restrict__ off, uint2* __restrict__ pairs,
                                                 int E, int NB, int NT) {
    __shared__ int lh[512];
    __shared__ int lp[512];
    __shared__ uint2 lpair[TS];
    int t = blockIdx.x, tid = threadIdx.x;
    lh[tid] = 0;
    __syncthreads();
    int e0 = t * TS;
    int sv[TS / 512], dv[TS / 512], rk[TS / 512];
    #pragma unroll
    for (int j = 0; j < TS / 512; ++j) {
        int e = e0 + j * 512 + tid;
        if (e < E) {
            int dd = dst[e];
            sv[j] = src[e];
            dv[j] = dd;
            rk[j] = atomicAdd(&lh[dd >> BSH], 1);
        } else dv[j] = -1;
    }
    __syncthreads();
    int own = lh[tid];
    lp[tid] = own;
    __syncthreads();
    for (int d = 1; d < 512; d <<= 1) {
        int v = (tid >= d) ? lp[tid - d] : 0;
        __syncthreads();
        lp[tid] += v;
        __syncthreads();
    }
    int excl = lp[tid] - own;
    __syncthreads();
    lh[tid] = excl;
    __syncthreads();
    #pragma unroll
    for (int j = 0; j < TS / 512; ++j) {
        if (dv[j] >= 0) {
            int pos = lh[dv[j] >> BSH] + rk[j];
            lpair[pos] = make_uint2((unsigned)sv[j], (unsigned)dv[j]);
        }
    }
    __syncthreads();
    for (int b = tid; b < NB; b += 512) lp[b] = off[b * NT + t];
    __syncthreads();
    int nloc = min(TS, E - e0);
    for (int i = tid; i < nloc; i += 512) {
        uint2 p = lpair[i];
        int b = (int)(p.y >> BSH);
        pairs[lp[b] + (i - lh[b])] = p;
    }
}

__global__ __launch_bounds__(256) void k_fine(const uint2* __restrict__ pairs, const int* __restrict__ base,
                                              const int* __restrict__ total, int* __restrict__ eidx,
                                              int* __restrict__ deg, int* __restrict__ start, int N) {
    __shared__ int cnt[128], pref[128];
    __shared__ int ssrc[FCAP];
    __shared__ unsigned short sln[FCAP], srk[FCAP];
    int b = blockIdx.x, tid = threadIdx.x;
    int n0 = b << BSH;
    int nn = min(128, N - n0);
    int eb = base[b];
    int ec = min(total[b], FCAP);
    if (tid < 128) cnt[tid] = 0;
    __syncthreads();
    for (int i = tid; i < ec; i += 256) {
        uint2 p = pairs[eb + i];
        int ln = (int)p.y - n0;
        int r = atomicAdd(&cnt[ln], 1);
        ssrc[i] = (int)p.x;
        sln[i] = (unsigned short)ln;
        srk[i] = (unsigned short)r;
    }
    __syncthreads();
    if (tid < 128) pref[tid] = cnt[tid];
    __syncthreads();
    for (int d = 1; d < 128; d <<= 1) {
        int v = 0;
        if (tid < 128 && tid >= d) v = pref[tid - d];
        __syncthreads();
        if (tid < 128) pref[tid] += v;
        __syncthreads();
    }
    if (tid < nn) {
        deg[n0 + tid] = cnt[tid];
        start[n0 + tid] = eb + pref[tid] - cnt[tid];
    }
    for (int i = tid; i < ec; i += 256) {
        int ln = sln[i];
        int pos = pref[ln] - cnt[ln] + srk[i];
        eidx[eb + pos] = ssrc[i];
    }
}

// ---------------- converts ----------------
__global__ __launch_bounds__(256) void k_cvt_x(const float* __restrict__ x, unsigned short* __restrict__ h, int total4) {
    int i = blockIdx.x * 256 + threadIdx.x;
    if (i >= total4) return;
    float4 v = ((const float4*)x)[i];
    ushort4 o;
    o.x = f2bf(v.x); o.y = f2bf(v.y); o.z = f2bf(v.z); o.w = f2bf(v.w);
    ((ushort4*)h)[i] = o;
}

__global__ __launch_bounds__(256) void k_cvt_w(const float* Wr0, const float* Wo0, const float* Wr1, const float* Wo1,
                                               const float* Wr2, const float* Wo2, const float* Wr3, const float* Wo3,
                                               unsigned short* __restrict__ Wcat) {
    int l = blockIdx.y;
    const float* Wr = (l == 0) ? Wr0 : (l == 1) ? Wr1 : (l == 2) ? Wr2 : Wr3;
    const float* Wo = (l == 0) ? Wo0 : (l == 1) ? Wo1 : (l == 2) ? Wo2 : Wo3;
    int idx = blockIdx.x * 256 + threadIdx.x;
    int j = idx >> 8, k = idx & 255;
    float v = (k < 128) ? Wr[j * 128 + k] : Wo[j * 128 + (k - 128)];
    Wcat[(size_t)l * 32768 + idx] = f2bf(v);
}

// ---------------- aggregation: one wave per node, 16 lanes x uint4 per row ----------------
// lane = g*16 + c: group g in [0,4) = edge slot, c in [0,16) = uint4 column.
// 4 edges gathered per load instruction (vs 1 before); 2-chunk unroll = 8 edges in flight.
__global__ __launch_bounds__(256) void k_agg(const unsigned short* __restrict__ h, const int* __restrict__ start,
                                             const int* __restrict__ deg, const int* __restrict__ eidx,
                                             unsigned short* __restrict__ agg, int N) {
    int w = blockIdx.x * 4 + (threadIdx.x >> 6);
    if (w >= N) return;
    int lane = threadIdx.x & 63;
    int g = lane >> 4;
    int c = lane & 15;
    int s = start[w];
    int d = deg[w];
    const uint4* h4 = (const uint4*)h;
    float a0 = 0.f, a1 = 0.f, a2 = 0.f, a3 = 0.f, a4 = 0.f, a5 = 0.f, a6 = 0.f, a7 = 0.f;
    int e = 0;
    while (e < d) {
        int nb = min(64, d - e);
        int myidx = (lane < nb) ? eidx[s + e + lane] : 0;
        for (int j = 0; j < nb; j += 8) {
            int e0 = j + g, e1 = j + 4 + g;
            int i0 = __shfl(myidx, e0 & 63);
            int i1 = __shfl(myidx, e1 & 63);
            uint4 u0 = make_uint4(0u, 0u, 0u, 0u), u1 = u0;
            if (e0 < nb) u0 = h4[(size_t)i0 * 16 + c];
            if (e1 < nb) u1 = h4[(size_t)i1 * 16 + c];
            a0 += bflo(u0.x) + bflo(u1.x);  a1 += bfhi(u0.x) + bfhi(u1.x);
            a2 += bflo(u0.y) + bflo(u1.y);  a3 += bfhi(u0.y) + bfhi(u1.y);
            a4 += bflo(u0.z) + bflo(u1.z);  a5 += bfhi(u0.z) + bfhi(u1.z);
            a6 += bflo(u0.w) + bflo(u1.w);  a7 += bfhi(u0.w) + bfhi(u1.w);
        }
        e += nb;
    }
    // reduce across the 4 edge-slot groups (lanes l, l+16, l+32, l+48)
    a0 += __shfl_down(a0, 32); a1 += __shfl_down(a1, 32);
    a2 += __shfl_down(a2, 32); a3 += __shfl_down(a3, 32);
    a4 += __shfl_down(a4, 32); a5 += __shfl_down(a5, 32);
    a6 += __shfl_down(a6, 32); a7 += __shfl_down(a7, 32);
    a0 += __shfl_down(a0, 16); a1 += __shfl_down(a1, 16);
    a2 += __shfl_down(a2, 16); a3 += __shfl_down(a3, 16);
    a4 += __shfl_down(a4, 16); a5 += __shfl_down(a5, 16);
    a6 += __shfl_down(a6, 16); a7 += __shfl_down(a7, 16);
    if (g == 0) {
        uint4 o;
        o.x = (unsigned)f2bf(a0) | ((unsigned)f2bf(a1) << 16);
        o.y = (unsigned)f2bf(a2) | ((unsigned)f2bf(a3) << 16);
        o.z = (unsigned)f2bf(a4) | ((unsigned)f2bf(a5) << 16);
        o.w = (unsigned)f2bf(a6) | ((unsigned)f2bf(a7) << 16);
        ((uint4*)agg)[(size_t)w * 16 + c] = o;
    }
}

// ---------------- fused conv via MFMA: hout = relu([agg|hin] @ Wcat^T + br) ----------------
__global__ __launch_bounds__(256) void k_conv(const unsigned short* __restrict__ agg, const unsigned short* __restrict__ hin,
                                              const unsigned short* __restrict__ Wcat, const float* __restrict__ br,
                                              unsigned short* __restrict__ hout, int N) {
    __shared__ unsigned short sA[128][40];
    __shared__ unsigned short sB[128][40];
    int tid = threadIdx.x;
    int wave = tid >> 6, lane = tid & 63;
    int wr = wave >> 1, wc = wave & 1;
    int m0 = wr * 64, n0 = wc * 64;
    int lm = lane & 15, quad = lane >> 4;
    int nbase = blockIdx.x * 128;

    floatx4 acc[4][4];
    #pragma unroll
    for (int mt = 0; mt < 4; ++mt)
        #pragma unroll
        for (int nt = 0; nt < 4; ++nt)
            acc[mt][nt] = {0.f, 0.f, 0.f, 0.f};

    int r = tid >> 1;
    int p = tid & 1;

    for (int s = 0; s < 8; ++s) {
        const unsigned short* srcA = (s < 4) ? agg : hin;
        int koff = (s & 3) * 32;
        const unsigned short* ga = srcA + (size_t)(nbase + r) * HD + koff + p * 16;
        *(uint4*)&sA[r][p * 16]     = *(const uint4*)ga;
        *(uint4*)&sA[r][p * 16 + 8] = *(const uint4*)(ga + 8);
        const unsigned short* gb = Wcat + (size_t)r * 256 + s * 32 + p * 16;
        *(uint4*)&sB[r][p * 16]     = *(const uint4*)gb;
        *(uint4*)&sB[r][p * 16 + 8] = *(const uint4*)(gb + 8);
        __syncthreads();
        bf16x8 af[4], bfr[4];
        #pragma unroll
        for (int mt = 0; mt < 4; ++mt) af[mt]  = *(const bf16x8*)&sA[m0 + mt * 16 + lm][quad * 8];
        #pragma unroll
        for (int nt = 0; nt < 4; ++nt) bfr[nt] = *(const bf16x8*)&sB[n0 + nt * 16 + lm][quad * 8];
        #pragma unroll
        for (int mt = 0; mt < 4; ++mt)
            #pragma unroll
            for (int nt = 0; nt < 4; ++nt)
                acc[mt][nt] = __builtin_amdgcn_mfma_f32_16x16x32_bf16(af[mt], bfr[nt], acc[mt][nt], 0, 0, 0);
        __syncthreads();
    }

    #pragma unroll
    for (int nt = 0; nt < 4; ++nt) {
        int col = n0 + nt * 16 + lm;
        float bias = br[col];
        #pragma unroll
        for (int mt = 0; mt < 4; ++mt) {
            int row0 = nbase + m0 + mt * 16 + quad * 4;
            #pragma unroll
            for (int reg = 0; reg < 4; ++reg) {
                int rr = row0 + reg;
                if (rr < N) {
                    float v = fmaxf(acc[mt][nt][reg] + bias, 0.f);
                    hout[(size_t)rr * HD + col] = f2bf(v);
                }
            }
        }
    }
}

// ---------------- pooling: one block per graph (batch sorted), no atomics ----------------
__device__ inline int lbound(const int* __restrict__ a, int n, int v) {
    int lo = 0, hi = n;
    while (lo < hi) { int m = (lo + hi) >> 1; if (a[m] < v) lo = m + 1; else hi = m; }
    return lo;
}

__global__ __launch_bounds__(256) void k_pool(const unsigned short* __restrict__ h, const int* __restrict__ batch,
                                              float* __restrict__ emb, int N) {
    __shared__ float red[16][128];
    int g = blockIdx.x, tid = threadIdx.x;
    int lo = lbound(batch, N, g);
    int hi = lbound(batch, N, g + 1);
    int slot = tid >> 4, c = tid & 15;
    const uint4* h4 = (const uint4*)h;
    float a0 = 0.f, a1 = 0.f, a2 = 0.f, a3 = 0.f, a4 = 0.f, a5 = 0.f, a6 = 0.f, a7 = 0.f;
    for (int r = lo + slot; r < hi; r += 16) {
        uint4 u = h4[(size_t)r * 16 + c];
        a0 += bflo(u.x); a1 += bfhi(u.x);
        a2 += bflo(u.y); a3 += bfhi(u.y);
        a4 += bflo(u.z); a5 += bfhi(u.z);
        a6 += bflo(u.w); a7 += bfhi(u.w);
    }
    red[slot][c * 8 + 0] = a0; red[slot][c * 8 + 1] = a1;
    red[slot][c * 8 + 2] = a2; red[slot][c * 8 + 3] = a3;
    red[slot][c * 8 + 4] = a4; red[slot][c * 8 + 5] = a5;
    red[slot][c * 8 + 6] = a6; red[slot][c * 8 + 7] = a7;
    __syncthreads();
    if (tid < 128) {
        float s = 0.f;
        #pragma unroll
        for (int k = 0; k < 16; ++k) s += red[k][tid];
        float cc = fmaxf((float)(hi - lo), 1.0f);
        emb[g * HD + tid] = s / cc;       // already the mean
    }
}

// ---------------- final linear (emb already mean) ----------------
__global__ __launch_bounds__(128) void k_final(const float* __restrict__ emb,
                                               const float* __restrict__ lw, const float* __restrict__ lb,
                                               float* __restrict__ out, int G) {
    int idx = blockIdx.x * 128 + threadIdx.x;
    if (idx >= G * CLS) return;
    int g = idx / CLS, c = idx % CLS;
    const float* e = emb + g * HD;
    const float* w = lw + c * HD;
    float s = 0.f;
    #pragma unroll
    for (int k = 0; k < HD; ++k) s += e[k] * w[k];
    out[idx] = s + lb[c];
}

extern "C" void kernel_launch(void* const* d_in, const int* in_sizes, int n_in,
                              void* d_out, int out_size, void* d_ws, size_t ws_size,
                              hipStream_t stream) {
    const float* x     = (const float*)d_in[0];
    const int*   ei    = (const int*)d_in[1];
    const int*   batch = (const int*)d_in[2];
    const float* Wr[4]  = {(const float*)d_in[3], (const float*)d_in[6], (const float*)d_in[9],  (const float*)d_in[12]};
    const float* brl[4] = {(const float*)d_in[4], (const float*)d_in[7], (const float*)d_in[10], (const float*)d_in[13]};
    const float* Wo[4]  = {(const float*)d_in[5], (const float*)d_in[8], (const float*)d_in[11], (const float*)d_in[14]};
    const float* lw = (const float*)d_in[15];
    const float* lb = (const float*)d_in[16];
    float* out = (float*)d_out;

    int N = in_sizes[0] / HD;
    int E = in_sizes[1] / 2;
    int G = out_size / CLS;
    int Np = (N + 127) & ~127;
    int NB = (N + 127) >> 7;
    int NT = (E + TS - 1) / TS;
    const int* src = ei;
    const int* dst = ei + E;

    // ---- workspace layout (zero-needed regions first) ----
    char* ws = (char*)d_ws;
    size_t off_b = 0;
    auto alloc = [&](size_t bytes) -> char* {
        char* p = ws + off_b;
        off_b += (bytes + 255) & ~(size_t)255;
        return p;
    };
    int*   total  = (int*)alloc((size_t)NB * 4);       // zeroed
    size_t zero_bytes = off_b;
    int*   base   = (int*)alloc((size_t)NB * 4);
    int*   hist   = (int*)alloc((size_t)NB * NT * 4);
    int*   offv   = (int*)alloc((size_t)NB * NT * 4);
    uint2* pairs  = (uint2*)alloc((size_t)E * 8);
    int*   eidx   = (int*)alloc((size_t)E * 4);
    int*   deg    = (int*)alloc((size_t)N * 4);
    int*   startp = (int*)alloc((size_t)N * 4);
    float* emb    = (float*)alloc((size_t)G * HD * 4);
    unsigned short* hbuf0 = (unsigned short*)alloc((size_t)Np * HD * 2);
    unsigned short* hbuf1 = (unsigned short*)alloc((size_t)Np * HD * 2);
    unsigned short* aggb  = (unsigned short*)alloc((size_t)Np * HD * 2);
    unsigned short* Wcat  = (unsigned short*)alloc((size_t)4 * 128 * 256 * 2);

    hipMemsetAsync(d_ws, 0, zero_bytes, stream);

    // ---- CSR build (counting sort) ----
    k_hist<<<NT, 256, 0, stream>>>(dst, hist, total, E, NB, NT);
    k_scan1<<<1, 512, 0, stream>>>(total, base, NB);
    k_scan2<<<NB, 256, 0, stream>>>(hist, base, offv, NT);
    k_scatter<<<NT, 512, 0, stream>>>(src, dst, offv, pairs, E, NB, NT);
    k_fine<<<NB, 256, 0, stream>>>(pairs, base, total, eidx, deg, startp, N);

    // ---- converts ----
    int total4 = N * HD / 4;
    k_cvt_x<<<(total4 + 255) / 256, 256, 0, stream>>>(x, hbuf0, total4);
    dim3 wgrid(128, 4);
    k_cvt_w<<<wgrid, 256, 0, stream>>>(Wr[0], Wo[0], Wr[1], Wo[1], Wr[2], Wo[2], Wr[3], Wo[3], Wcat);

    // ---- 4 GraphConv layers ----
    unsigned short* hcur = hbuf0;
    unsigned short* hnxt = hbuf1;
    for (int l = 0; l < 4; ++l) {
        k_agg<<<(N + 3) / 4, 256, 0, stream>>>(hcur, startp, deg, eidx, aggb, N);
        k_conv<<<Np / 128, 256, 0, stream>>>(aggb, hcur, Wcat + (size_t)l * 32768, brl[l], hnxt, N);
        unsigned short* t = hcur; hcur = hnxt; hnxt = t;
    }

    // ---- pooling + final linear ----
    k_pool<<<G, 256, 0, stream>>>(hcur, batch, emb, N);
    k_final<<<(G * CLS + 127) / 128, 128, 0, stream>>>(emb, lw, lb, out, G);
}